// Round 19
// baseline (549.061 us; speedup 1.0000x reference)
//
#include <hip/hip_runtime.h>
#include <hip/hip_bf16.h>

typedef __attribute__((ext_vector_type(8))) short bf16x8;
typedef __attribute__((ext_vector_type(4))) short bf16x4;
typedef __attribute__((ext_vector_type(4))) float f32x4;

constexpr int NT   = 512;   // tiles
constexpr int NP   = 512;   // points (M)
constexpr int DIN  = 256;   // K
constexpr int DOUT = 256;   // N

__device__ __forceinline__ short f2bf(float f) {
  __hip_bfloat16 h = __float2bfloat16(f);
  return __builtin_bit_cast(short, h);
}

__device__ __forceinline__ bf16x8 cvt8(f32x4 a, f32x4 b) {
  bf16x8 r;
  r[0] = f2bf(a[0]); r[1] = f2bf(a[1]); r[2] = f2bf(a[2]); r[3] = f2bf(a[3]);
  r[4] = f2bf(b[0]); r[5] = f2bf(b[1]); r[6] = f2bf(b[2]); r[7] = f2bf(b[3]);
  return r;
}

// Ws: [n=256][k=256] bf16, 128 KB. Granule = 8 elem (16 B).
// g(n) = (n ^ (n>>2)) & 7: B-frag reads (16 consecutive n, fixed k) are
// 2-way (free); transpose staging writes 8-way.
__device__ __forceinline__ int wsw(int n, int k) {
  return n * DIN + (k ^ (((n ^ (n >> 2)) & 7) << 3));
}

// LDS (128 KB) already limits us to 1 block/CU (8 waves), so the register
// bound can be fully relaxed: (512,1) allows up to 256 VGPR/wave with no
// occupancy loss. (512,2) capped at 128 VGPR and spilled ~20 regs to
// scratch -> the v9/v10 FETCH/WRITE blowups.
__global__ __launch_bounds__(512, 1) void adaptive_linear_v11(
    const float* __restrict__ x,     // [NT][NP][DIN]
    const int*   __restrict__ idx,   // [NT]
    const float* __restrict__ w,     // [CH][DIN][DOUT]
    const float* __restrict__ bias,  // [DOUT]
    float*       __restrict__ out)   // [NT][NP][DOUT]
{
  __shared__ short Ws[DOUT * DIN];   // 128 KB; x never touches LDS

  const int tid = threadIdx.x;
  const int t   = blockIdx.x;

  const int c = idx[t];
  const float* xb = x   + (size_t)t * NP * DIN;
  const float* wb = w   + (size_t)c * DIN * DOUT;
  float*       ob = out + (size_t)t * NP * DOUT;

  // ---- W staging (all 8 waves, prologue only; v8-proven) ----------------
  {
    const int wl = tid & 63;
    const int wv = tid >> 6;
    f32x4 wr[8];
    #pragma unroll 1
    for (int ss = 0; ss < 4; ++ss) {
      const float* ws = wb + (size_t)(ss * 64 + wv * 8) * DOUT + wl * 4;
      #pragma unroll
      for (int q = 0; q < 8; ++q)
        wr[q] = *reinterpret_cast<const f32x4*>(ws + (size_t)q * DOUT);
      #pragma unroll
      for (int h = 0; h < 2; ++h) {
        const int k0 = ss * 64 + wv * 8 + h * 4;
        #pragma unroll
        for (int j = 0; j < 4; ++j) {
          bf16x4 v = { f2bf(wr[h*4+0][j]), f2bf(wr[h*4+1][j]),
                       f2bf(wr[h*4+2][j]), f2bf(wr[h*4+3][j]) };
          *reinterpret_cast<bf16x4*>(&Ws[wsw(wl * 4 + j, k0)]) = v;
        }
      }
    }
  }
  __syncthreads();                   // the ONLY barrier in the kernel

  // ---- self-paced waves: 16 rows x 256 cols per wave per strip ----------
  const int l    = tid & 63;
  const int wid  = tid >> 6;         // 0..7
  const int lrow = l & 15;
  const int lk   = l >> 4;           // 0..3

  float bvv[16];
  #pragma unroll
  for (int fn = 0; fn < 16; ++fn)
    bvv[fn] = bias[fn * 16 + lrow];

  #pragma unroll 1
  for (int strip = 0; strip < 4; ++strip) {
    const int rows = strip * 128 + wid * 16;
    const float* xs0 = xb + (size_t)(rows + lrow) * DIN + lk * 8;

    f32x4 acc[16];
    #pragma unroll
    for (int fn = 0; fn < 16; ++fn)
      acc[fn] = f32x4{0.f, 0.f, 0.f, 0.f};

    // 4-deep A prefetch ring; all indices static (full unroll)
    f32x4 ar[4][2];
    #define LOADA(KS, BUF)                                                   \
      {                                                                      \
        const float* p = xs0 + (KS) * 32;                                    \
        ar[BUF][0] = *reinterpret_cast<const f32x4*>(p);                     \
        ar[BUF][1] = *reinterpret_cast<const f32x4*>(p + 4);                 \
      }

    LOADA(0, 0)
    LOADA(1, 1)
    LOADA(2, 2)
    LOADA(3, 3)

    #pragma unroll
    for (int ks = 0; ks < 8; ++ks) {
      bf16x8 a = cvt8(ar[ks % 4][0], ar[ks % 4][1]);
      if (ks < 4) {
        // prefetch ks+4 into the buffer just freed
        LOADA(ks + 4, ks % 4)
      }

      const int kb = ks * 32 + lk * 8;
      __builtin_amdgcn_s_setprio(1);
      #pragma unroll
      for (int g = 0; g < 4; ++g) {      // 4 groups of 4 n-frags
        bf16x8 b[4];
        #pragma unroll
        for (int j = 0; j < 4; ++j)
          b[j] = *reinterpret_cast<const bf16x8*>(
              &Ws[wsw((g * 4 + j) * 16 + lrow, kb)]);
        #pragma unroll
        for (int j = 0; j < 4; ++j)
          acc[g * 4 + j] = __builtin_amdgcn_mfma_f32_16x16x32_bf16(
              a, b[j], acc[g * 4 + j], 0, 0, 0);
      }
      __builtin_amdgcn_s_setprio(0);
    }
    #undef LOADA

    // ---- epilogue: bias + plain f32 stores ------------------------------
    const int r0w = rows + lk * 4;
    #pragma unroll
    for (int fn = 0; fn < 16; ++fn) {
      const int col = fn * 16 + lrow;
      float* op = ob + (size_t)r0w * DOUT + col;
      #pragma unroll
      for (int rr = 0; rr < 4; ++rr)
        op[(size_t)rr * DOUT] = acc[fn][rr] + bvv[fn];
    }
  }
}

extern "C" void kernel_launch(void* const* d_in, const int* in_sizes, int n_in,
                              void* d_out, int out_size, void* d_ws, size_t ws_size,
                              hipStream_t stream) {
  const float* x    = (const float*)d_in[0];
  const int*   idx  = (const int*)d_in[1];
  const float* w    = (const float*)d_in[2];
  const float* bias = (const float*)d_in[3];
  float* out = (float*)d_out;

  adaptive_linear_v11<<<NT, 512, 0, stream>>>(x, idx, w, bias, out);
}

// Round 20
// 145.591 us; speedup vs baseline: 3.7712x; 3.7712x over previous
//
#include <hip/hip_runtime.h>
#include <hip/hip_bf16.h>

typedef __attribute__((ext_vector_type(8))) short bf16x8;
typedef __attribute__((ext_vector_type(4))) short bf16x4;
typedef __attribute__((ext_vector_type(4))) float f32x4;

constexpr int NT   = 512;   // tiles
constexpr int NP   = 512;   // points (M)
constexpr int DIN  = 256;   // K
constexpr int DOUT = 256;   // N
constexpr int BN   = 128;   // N-half per block
constexpr int CHM  = 32;    // M rows per epoch
constexpr int NEP  = NP / CHM;  // 16 epochs

__device__ __forceinline__ short f2bf(float f) {
  __hip_bfloat16 h = __float2bfloat16(f);
  return __builtin_bit_cast(short, h);
}

// Workgroup barrier WITHOUT the vmcnt(0) drain __syncthreads() implies.
__device__ __forceinline__ void wg_barrier() {
  asm volatile("s_waitcnt lgkmcnt(0)" ::: "memory");
  __builtin_amdgcn_s_barrier();
  __builtin_amdgcn_sched_barrier(0);
}

// Ws: [n=128][k=256] bf16, 64 KB. Granule = 8 elem (16 B).
__device__ __forceinline__ int wsw(int n, int k) {
  return n * DIN + (k ^ (((n ^ (n >> 2)) & 7) << 3));
}

// Xs: [m=32][k=256] bf16, 16 KB.
__device__ __forceinline__ int xsw(int m, int k) {
  return m * DIN + (k ^ ((m & 7) << 3));
}

__global__ __launch_bounds__(512, 4) void adaptive_linear_v12(
    const float* __restrict__ x,     // [NT][NP][DIN]
    const int*   __restrict__ idx,   // [NT]
    const float* __restrict__ w,     // [CH][DIN][DOUT]
    const float* __restrict__ bias,  // [DOUT]
    float*       __restrict__ out)   // [NT][NP][DOUT]
{
  __shared__ short Ws[BN * DIN];     // 64 KB
  __shared__ short Xs[CHM * DIN];    // 16 KB  (80 KB total -> 2 blocks/CU)

  const int tid = threadIdx.x;
  const int b   = blockIdx.x;
  // XCD pairing: blocks b and b+8 share a tile (same dispatch class mod 8
  // -> same XCD -> second x-read hits that XCD's L2).
  const int t   = (b >> 4) * 8 + (b & 7);
  const int nh  = (b >> 3) & 1;

  const int c = idx[t];
  const float* xb = x   + (size_t)t * NP * DIN;
  const float* wb = w   + (size_t)c * DIN * DOUT + nh * BN;
  float*       ob = out + (size_t)t * NP * DOUT + nh * BN;

  // ---- W staging: half channel, 4 slabs of 64 k-rows --------------------
  // lanes: n4 = (tid&31)*4 spans 128 cols; kg = tid>>5 spans 16 k-subrows.
  {
    const int n4 = (tid & 31) * 4;
    const int kg = tid >> 5;
    f32x4 wr[4];
    #pragma unroll 1
    for (int ss = 0; ss < 4; ++ss) {
      const int k0 = ss * 64 + kg * 4;
      const float* src = wb + (size_t)k0 * DOUT + n4;
      #pragma unroll
      for (int r = 0; r < 4; ++r)
        wr[r] = *reinterpret_cast<const f32x4*>(src + (size_t)r * DOUT);
      #pragma unroll
      for (int j = 0; j < 4; ++j) {
        bf16x4 v = { f2bf(wr[0][j]), f2bf(wr[1][j]),
                     f2bf(wr[2][j]), f2bf(wr[3][j]) };
        *reinterpret_cast<bf16x4*>(&Ws[wsw(n4 + j, k0)]) = v;
      }
    }
  }

  // ---- x staging: 32-row chunk; instr i reads 8 KB contiguous -----------
  f32x4 xr[4];
  auto load_x = [&](int e) {
    const float* base = xb + (size_t)e * CHM * DIN;
    #pragma unroll
    for (int i = 0; i < 4; ++i)
      xr[i] = *reinterpret_cast<const f32x4*>(base + i * 2048 + tid * 4);
  };
  auto write_x = [&]() {
    const int m0 = tid >> 6;
    const int k  = (tid & 63) * 4;
    #pragma unroll
    for (int i = 0; i < 4; ++i) {
      bf16x4 v = { f2bf(xr[i][0]), f2bf(xr[i][1]),
                   f2bf(xr[i][2]), f2bf(xr[i][3]) };
      *reinterpret_cast<bf16x4*>(&Xs[xsw(m0 + i * 8, k)]) = v;
    }
  };

  // ---- wave decomposition: 2 (M) x 4 (N); wave owns 16 x 32 -------------
  const int l    = tid & 63;
  const int wid  = tid >> 6;
  const int wm   = wid >> 2;           // 0..1
  const int wn   = wid & 3;            // 0..3
  const int lrow = l & 15;
  const int lk   = l >> 4;             // 0..3

  float bv[2];
  #pragma unroll
  for (int fn = 0; fn < 2; ++fn)
    bv[fn] = bias[nh * BN + wn * 32 + fn * 16 + lrow];

  // ---- prologue ---------------------------------------------------------
  load_x(0);
  write_x();               // counted vmcnt on xr only (W stage ran above)
  wg_barrier();

  for (int e = 0; e < NEP; ++e) {
    // 1. issue next epoch's x loads early — fly under compute
    if (e < NEP - 1) load_x(e + 1);

    // 2. full-K compute for this 32-row chunk
    f32x4 acc[2][2] = {};
    #pragma unroll
    for (int ks = 0; ks < 8; ++ks) {
      const int kb = ks * 32 + lk * 8;
      bf16x8 a[2], bb[2];
      #pragma unroll
      for (int fm = 0; fm < 2; ++fm)
        a[fm] = *reinterpret_cast<const bf16x8*>(
            &Xs[xsw(wm * 16 + fm * 8, kb)]);
      // note: rows per M-wave = 16; a-frag rows are wm*16+lrow (lrow<16)
      a[0] = *reinterpret_cast<const bf16x8*>(&Xs[xsw(wm * 16 + lrow, kb)]);
      #pragma unroll
      for (int fn = 0; fn < 2; ++fn)
        bb[fn] = *reinterpret_cast<const bf16x8*>(
            &Ws[wsw(wn * 32 + fn * 16 + lrow, kb)]);
      #pragma unroll
      for (int fn = 0; fn < 2; ++fn)
        acc[0][fn] = __builtin_amdgcn_mfma_f32_16x16x32_bf16(
            a[0], bb[fn], acc[0][fn], 0, 0, 0);
    }

    // 3. epilogue: bias + plain f32 stores
    {
      const int r0w = e * CHM + wm * 16 + lk * 4;
      #pragma unroll
      for (int fn = 0; fn < 2; ++fn) {
        const int col = wn * 32 + fn * 16 + lrow;
        float* op = ob + (size_t)r0w * DOUT + col;
        #pragma unroll
        for (int rr = 0; rr < 4; ++rr)
          op[(size_t)rr * DOUT] = acc[0][fn][rr] + bv[fn];
      }
    }

    // 4. publish next chunk
    if (e < NEP - 1) {
      wg_barrier();        // all waves done reading Xs
      write_x();
      wg_barrier();        // Xs(e+1) visible
    }
  }
}

extern "C" void kernel_launch(void* const* d_in, const int* in_sizes, int n_in,
                              void* d_out, int out_size, void* d_ws, size_t ws_size,
                              hipStream_t stream) {
  const float* x    = (const float*)d_in[0];
  const int*   idx  = (const int*)d_in[1];
  const float* w    = (const float*)d_in[2];
  const float* bias = (const float*)d_in[3];
  float* out = (float*)d_out;

  adaptive_linear_v12<<<NT * 2, 512, 0, stream>>>(x, idx, w, bias, out);
}

// Round 21
// 129.395 us; speedup vs baseline: 4.2433x; 1.1252x over previous
//
#include <hip/hip_runtime.h>
#include <hip/hip_bf16.h>

typedef __attribute__((ext_vector_type(8))) short bf16x8;
typedef __attribute__((ext_vector_type(4))) short bf16x4;
typedef __attribute__((ext_vector_type(4))) float f32x4;

constexpr int NT   = 512;   // tiles
constexpr int NP   = 512;   // points (M)
constexpr int DIN  = 256;   // K
constexpr int DOUT = 256;   // N
constexpr int BN   = 128;   // N-half per block
constexpr int CHM  = 64;    // M rows per epoch
constexpr int NEP  = NP / CHM;  // 8 epochs

__device__ __forceinline__ short f2bf(float f) {
  __hip_bfloat16 h = __float2bfloat16(f);
  return __builtin_bit_cast(short, h);
}

// Workgroup barrier WITHOUT the vmcnt(0) drain __syncthreads() implies.
__device__ __forceinline__ void wg_barrier() {
  asm volatile("s_waitcnt lgkmcnt(0)" ::: "memory");
  __builtin_amdgcn_s_barrier();
  __builtin_amdgcn_sched_barrier(0);
}

// Ws: [n=128][k=256] bf16, 64 KB. Granule = 8 elem (16 B).
__device__ __forceinline__ int wsw(int n, int k) {
  return n * DIN + (k ^ (((n ^ (n >> 2)) & 7) << 3));
}

// Xs: [m=64][k=256] bf16, 32 KB per buffer.
__device__ __forceinline__ int xsw(int m, int k) {
  return m * DIN + (k ^ ((m & 7) << 3));
}

__global__ __launch_bounds__(512, 2) void adaptive_linear_v13(
    const float* __restrict__ x,     // [NT][NP][DIN]
    const int*   __restrict__ idx,   // [NT]
    const float* __restrict__ w,     // [CH][DIN][DOUT]
    const float* __restrict__ bias,  // [DOUT]
    float*       __restrict__ out)   // [NT][NP][DOUT]
{
  __shared__ short Ws[BN * DIN];      // 64 KB
  __shared__ short Xs[2][CHM * DIN];  // 2 x 32 KB  (128 KB total)

  const int tid = threadIdx.x;
  const int b   = blockIdx.x;
  // XCD pairing (v12-proven): blocks b and b+8 share a tile -> same XCD
  // round-robin -> the pair's second x-read hits that XCD's L2.
  const int t   = (b >> 4) * 8 + (b & 7);
  const int nh  = (b >> 3) & 1;

  const int c = idx[t];
  const float* xb = x   + (size_t)t * NP * DIN;
  const float* wb = w   + (size_t)c * DIN * DOUT + nh * BN;
  float*       ob = out + (size_t)t * NP * DOUT + nh * BN;

  const int l   = tid & 63;
  const int wid = tid >> 6;            // 0..7

  // ---- W staging (all 8 waves, prologue only; v12-proven) ---------------
  {
    const int n4 = (tid & 31) * 4;
    const int kg = tid >> 5;           // 0..15
    f32x4 wr[4];
    #pragma unroll 1
    for (int ss = 0; ss < 4; ++ss) {
      const int k0 = ss * 64 + kg * 4;
      const float* src = wb + (size_t)k0 * DOUT + n4;
      #pragma unroll
      for (int r = 0; r < 4; ++r)
        wr[r] = *reinterpret_cast<const f32x4*>(src + (size_t)r * DOUT);
      #pragma unroll
      for (int j = 0; j < 4; ++j) {
        bf16x4 v = { f2bf(wr[0][j]), f2bf(wr[1][j]),
                     f2bf(wr[2][j]), f2bf(wr[3][j]) };
        *reinterpret_cast<bf16x4*>(&Ws[wsw(n4 + j, k0)]) = v;
      }
    }
  }

  // ---- roles ------------------------------------------------------------
  const bool producer = (wid < 4);
  const int  p = wid;                  // producer: rows p*16 .. p*16+15
  const int  q = wid - 4;              // consumer: rows q*16 within chunk

  // producer: 16 full 1 KB row-loads back-to-back (64 staging VGPRs)
  f32x4 xr[16];
  auto load_x = [&](int e) {
    const float* base = xb + (size_t)e * CHM * DIN + (size_t)(p * 16) * DIN + l * 4;
    #pragma unroll
    for (int i = 0; i < 16; ++i)
      xr[i] = *reinterpret_cast<const f32x4*>(base + (size_t)i * DIN);
  };
  auto write_x = [&](int buf) {        // cvt + one b64 write per row
    #pragma unroll
    for (int i = 0; i < 16; ++i) {
      bf16x4 v = { f2bf(xr[i][0]), f2bf(xr[i][1]),
                   f2bf(xr[i][2]), f2bf(xr[i][3]) };
      *reinterpret_cast<bf16x4*>(&Xs[buf][xsw(p * 16 + i, l * 4)]) = v;
    }
  };

  // consumer state
  const int lrow = l & 15;
  const int lk   = l >> 4;             // 0..3
  float bv[8];
  if (!producer) {
    #pragma unroll
    for (int j = 0; j < 8; ++j)
      bv[j] = bias[nh * BN + j * 16 + lrow];
  }

  // ---- prologue ---------------------------------------------------------
  if (producer) load_x(0);             // flies under the W stage above
  if (producer) write_x(0);
  wg_barrier();

  // ---- main loop: 8 epochs ----------------------------------------------
  for (int e = 0; e < NEP; ++e) {
    if (producer) {
      if (e < NEP - 1) {
        load_x(e + 1);                 // 64 KB/CU burst in flight
        write_x((e + 1) & 1);          // counted vmcnt on xr only
      }
    } else {
      f32x4 acc[8] = {};
      const short* xbuf = Xs[e & 1];
      #pragma unroll
      for (int ks = 0; ks < 8; ++ks) {
        const int kb = ks * 32 + lk * 8;
        const bf16x8 a = *reinterpret_cast<const bf16x8*>(
            &xbuf[xsw(q * 16 + lrow, kb)]);
        #pragma unroll
        for (int j = 0; j < 8; ++j) {
          const bf16x8 bb = *reinterpret_cast<const bf16x8*>(
              &Ws[wsw(j * 16 + lrow, kb)]);
          acc[j] = __builtin_amdgcn_mfma_f32_16x16x32_bf16(a, bb, acc[j], 0, 0, 0);
        }
      }
      // epilogue: bias + plain f32 stores (stay async)
      const int r0w = e * CHM + q * 16 + lk * 4;
      #pragma unroll
      for (int j = 0; j < 8; ++j) {
        const int col = j * 16 + lrow;
        float* op = ob + (size_t)r0w * DOUT + col;
        #pragma unroll
        for (int rr = 0; rr < 4; ++rr)
          op[(size_t)rr * DOUT] = acc[j][rr] + bv[j];
      }
    }
    if (e < NEP - 1) wg_barrier();     // publish buffer swap
  }
}

extern "C" void kernel_launch(void* const* d_in, const int* in_sizes, int n_in,
                              void* d_out, int out_size, void* d_ws, size_t ws_size,
                              hipStream_t stream) {
  const float* x    = (const float*)d_in[0];
  const int*   idx  = (const int*)d_in[1];
  const float* w    = (const float*)d_in[2];
  const float* bias = (const float*)d_in[3];
  float* out = (float*)d_out;

  adaptive_linear_v13<<<NT * 2, 512, 0, stream>>>(x, idx, w, bias, out);
}